// Round 1
// baseline (52.387 us; speedup 1.0000x reference)
//
#include <hip/hip_runtime.h>
#include <hip/hip_bf16.h>

typedef __attribute__((ext_vector_type(8))) short short8;
typedef __attribute__((ext_vector_type(4))) float f32x4;

#define MFMA(a, b, c) __builtin_amdgcn_mfma_f32_16x16x32_bf16((a), (b), (c), 0, 0, 0)

__device__ __forceinline__ unsigned short f2bf(float f) {
  union { float f; unsigned int u; } v; v.f = f;
  unsigned int u = v.u;
  unsigned int r = u + 0x7FFFu + ((u >> 16) & 1u);  // RNE
  return (unsigned short)(r >> 16);
}

// ---------------------------------------------------------------------------
// k0: pack Wq|Wk|Wv (fp32 [384][64] each) into W3t bf16 [192 n][384 k] (transposed)
// ---------------------------------------------------------------------------
__global__ void wconv_kernel(const float* __restrict__ Wq, const float* __restrict__ Wk,
                             const float* __restrict__ Wv, unsigned short* __restrict__ W3t) {
  int n = blockIdx.x;   // 0..191
  int k = threadIdx.x;  // 0..383
  const float* src = (n < 64) ? Wq : ((n < 128) ? Wk : Wv);
  W3t[n * 384 + k] = f2bf(src[k * 64 + (n & 63)]);
}

// ---------------------------------------------------------------------------
// k1: QKV projection GEMM. M=65536, K=384, N=192 (Q|K|V).
// 256 threads = 4 waves; block tile 128(M) x 192(N); BK=32.
// Writes Qg, Kg bf16 row-major [65536][64]; V transposed: Vtg bf16 [256 b][64 h][256 tok].
// ---------------------------------------------------------------------------
__global__ __launch_bounds__(256) void proj_kernel(
    const float* __restrict__ x, const unsigned short* __restrict__ W3t,
    unsigned short* __restrict__ Qg, unsigned short* __restrict__ Kg,
    unsigned short* __restrict__ Vtg) {
  __shared__ unsigned short xl[128 * 40];  // [128][32+8pad] bf16, stride 80B (=5*16B)
  __shared__ unsigned short wl[192 * 40];  // [192][32+8pad] bf16 (W^T slice: [n][k])
  const int tid = threadIdx.x;
  const int w = tid >> 6, lane = tid & 63, g = lane >> 4, q = lane & 15;
  const long m0 = (long)blockIdx.x * 128;

  f32x4 acc[2][12];
  const f32x4 zf = {0.f, 0.f, 0.f, 0.f};
#pragma unroll
  for (int i = 0; i < 2; ++i)
#pragma unroll
    for (int j = 0; j < 12; ++j) acc[i][j] = zf;

  for (int k0 = 0; k0 < 384; k0 += 32) {
    if (k0) __syncthreads();
    // stage x tile: 128 rows x 32 cols, fp32 -> bf16
#pragma unroll
    for (int it = 0; it < 4; ++it) {
      int i = tid + it * 256;
      int r = i >> 3, c4 = (i & 7) * 4;
      const float4 vv = *(const float4*)&x[(m0 + r) * 384 + k0 + c4];
      ushort4 h;
      h.x = f2bf(vv.x); h.y = f2bf(vv.y); h.z = f2bf(vv.z); h.w = f2bf(vv.w);
      *(ushort4*)&xl[r * 40 + c4] = h;
    }
    // stage W^T slice: 192 rows (n) x 32 (k), already bf16
#pragma unroll
    for (int it = 0; it < 3; ++it) {
      int i = tid + it * 256;
      int n = i >> 2, koff = (i & 3) * 8;
      const uint4 vv = *(const uint4*)&W3t[n * 384 + k0 + koff];
      *(uint4*)&wl[n * 40 + koff] = vv;
    }
    __syncthreads();
    // A-frags: wave w owns rows [32w, 32w+32)
    short8 a0 = *(const short8*)&xl[(32 * w + q) * 40 + g * 8];
    short8 a1 = *(const short8*)&xl[(32 * w + 16 + q) * 40 + g * 8];
#pragma unroll
    for (int ct = 0; ct < 12; ++ct) {
      short8 bfr = *(const short8*)&wl[(16 * ct + q) * 40 + g * 8];
      acc[0][ct] = MFMA(a0, bfr, acc[0][ct]);
      acc[1][ct] = MFMA(a1, bfr, acc[1][ct]);
    }
  }

  // epilogue: D layout col=lane&15, row=(lane>>4)*4+reg
#pragma unroll
  for (int rt = 0; rt < 2; ++rt) {
    const long mb = m0 + 32 * w + 16 * rt + 4 * g;
#pragma unroll
    for (int ct = 0; ct < 12; ++ct) {
      int c = 16 * ct + q;
      unsigned short h0 = f2bf(acc[rt][ct][0]);
      unsigned short h1 = f2bf(acc[rt][ct][1]);
      unsigned short h2 = f2bf(acc[rt][ct][2]);
      unsigned short h3 = f2bf(acc[rt][ct][3]);
      if (ct < 4) {
        Qg[(mb + 0) * 64 + c] = h0; Qg[(mb + 1) * 64 + c] = h1;
        Qg[(mb + 2) * 64 + c] = h2; Qg[(mb + 3) * 64 + c] = h3;
      } else if (ct < 8) {
        int cc = c - 64;
        Kg[(mb + 0) * 64 + cc] = h0; Kg[(mb + 1) * 64 + cc] = h1;
        Kg[(mb + 2) * 64 + cc] = h2; Kg[(mb + 3) * 64 + cc] = h3;
      } else {
        int hh = c - 128;
        long bb = mb >> 8;
        int tok = (int)(mb & 255);  // 4 consecutive tokens (jr) -> 8B store
        ushort4 pk; pk.x = h0; pk.y = h1; pk.z = h2; pk.w = h3;
        *(ushort4*)&Vtg[(bb * 64 + hh) * 256 + tok] = pk;
      }
    }
  }
}

// ---------------------------------------------------------------------------
// k2: causal attention, one block per batch. 256 threads = 4 waves.
// LDS (dynamic 75776B): K [256][72] bf16 + V^T [64][264] bf16 + P xpose buf [4][16][40].
// Wave w handles row-tiles {w, 7-w, 8+w, 15-w} (balanced: 34 col-tile units each).
// ---------------------------------------------------------------------------
__global__ __launch_bounds__(256) void attn_kernel(
    const unsigned short* __restrict__ Qg, const unsigned short* __restrict__ Kg,
    const unsigned short* __restrict__ Vtg, float* __restrict__ out) {
  extern __shared__ unsigned short sm[];
  unsigned short* Kl = sm;            // [256][72]  stride 144B = 9*16B
  unsigned short* Vl = sm + 18432;    // [64][264]  stride 528B = 33*16B
  unsigned short* Pb = sm + 35328;    // [4 waves][16][40] stride 80B = 5*16B
  const int tid = threadIdx.x;
  const int w = tid >> 6, lane = tid & 63, g = lane >> 4, q = lane & 15;
  const int b = blockIdx.x;
  const unsigned short* Kgb = Kg + (long)b * 16384;
  const unsigned short* Vgb = Vtg + (long)b * 16384;

  // stage K row-major, V^T h-major (both padded)
#pragma unroll
  for (int it = 0; it < 8; ++it) {
    int i = tid + it * 256;
    int tok = i >> 3, k0 = (i & 7) * 8;
    *(uint4*)&Kl[tok * 72 + k0] = *(const uint4*)&Kgb[tok * 64 + k0];
  }
#pragma unroll
  for (int it = 0; it < 8; ++it) {
    int i = tid + it * 256;
    int h = i >> 5, t0 = (i & 31) * 8;
    *(uint4*)&Vl[h * 264 + t0] = *(const uint4*)&Vgb[h * 256 + t0];
  }
  __syncthreads();

  const int tt[4] = {w, 7 - w, 8 + w, 15 - w};
  const f32x4 zf = {0.f, 0.f, 0.f, 0.f};
#pragma unroll
  for (int ti = 0; ti < 4; ++ti) {
    const int t = tt[ti];
    // Q A-frags straight from global (read once, L2-resident)
    const unsigned short* Qrow = Qg + ((long)b * 256 + t * 16 + q) * 64;
    short8 aq0 = *(const short8*)&Qrow[g * 8];
    short8 aq1 = *(const short8*)&Qrow[32 + g * 8];

    f32x4 s[16];  // all indexing compile-time (unrolled) -> stays in VGPRs
#pragma unroll
    for (int j = 0; j < 16; ++j) {
      if (j <= t) {
        short8 bk0 = *(const short8*)&Kl[(16 * j + q) * 72 + g * 8];
        short8 bk1 = *(const short8*)&Kl[(16 * j + q) * 72 + 32 + g * 8];
        f32x4 sv = MFMA(aq0, bk0, zf);
        sv = MFMA(aq1, bk1, sv);
#pragma unroll
        for (int jr = 0; jr < 4; ++jr) {
          float v = sv[jr] * 0.125f;  // H^-0.5
          if (j == t && q > 4 * g + jr) v = -1e30f;  // causal mask (diagonal tile)
          sv[jr] = v;
        }
        s[j] = sv;
      }
    }

    // softmax: row r = 16t + 4g + jr lives in 16 lanes (same g), cols = lane&15
    float mrow[4], lrow[4];
#pragma unroll
    for (int jr = 0; jr < 4; ++jr) {
      float m = -1e30f;
#pragma unroll
      for (int j = 0; j < 16; ++j)
        if (j <= t) m = fmaxf(m, s[j][jr]);
      m = fmaxf(m, __shfl_xor(m, 1));
      m = fmaxf(m, __shfl_xor(m, 2));
      m = fmaxf(m, __shfl_xor(m, 4));
      m = fmaxf(m, __shfl_xor(m, 8));
      mrow[jr] = m;
    }
#pragma unroll
    for (int jr = 0; jr < 4; ++jr) {
      float l = 0.0f;
#pragma unroll
      for (int j = 0; j < 16; ++j)
        if (j <= t) {
          float p = __expf(s[j][jr] - mrow[jr]);
          s[j][jr] = p;
          l += p;
        }
      l += __shfl_xor(l, 1);
      l += __shfl_xor(l, 2);
      l += __shfl_xor(l, 4);
      l += __shfl_xor(l, 8);
      lrow[jr] = l;
    }

    // PV: per 32-token k-slice, transpose P through per-wave LDS buffer
    f32x4 o[4];
#pragma unroll
    for (int ct = 0; ct < 4; ++ct) o[ct] = zf;
#pragma unroll
    for (int ks = 0; ks < 8; ++ks) {
      if (2 * ks <= t) {
#pragma unroll
        for (int half = 0; half < 2; ++half) {
          int tile = 2 * ks + half;
#pragma unroll
          for (int jr = 0; jr < 4; ++jr) {
            unsigned short pv = 0;
            if (tile <= t) pv = f2bf(s[tile][jr]);
            Pb[w * 640 + (4 * g + jr) * 40 + half * 16 + q] = pv;
          }
        }
        short8 ap = *(const short8*)&Pb[w * 640 + q * 40 + g * 8];
#pragma unroll
        for (int ct = 0; ct < 4; ++ct) {
          short8 bv = *(const short8*)&Vl[(16 * ct + q) * 264 + ks * 32 + g * 8];
          o[ct] = MFMA(ap, bv, o[ct]);
        }
      }
    }

    // epilogue: out fp32 [b][tok][h], divide by row sum
    const long rowbase = (long)b * 256 + 16 * t + 4 * g;
#pragma unroll
    for (int jr = 0; jr < 4; ++jr) {
      float inv = 1.0f / lrow[jr];
#pragma unroll
      for (int ct = 0; ct < 4; ++ct) {
        out[(rowbase + jr) * 64 + 16 * ct + q] = o[ct][jr] * inv;
      }
    }
  }
}

// ---------------------------------------------------------------------------
extern "C" void kernel_launch(void* const* d_in, const int* in_sizes, int n_in,
                              void* d_out, int out_size, void* d_ws, size_t ws_size,
                              hipStream_t stream) {
  const float* x  = (const float*)d_in[0];
  const float* Wq = (const float*)d_in[1];
  const float* Wk = (const float*)d_in[2];
  const float* Wv = (const float*)d_in[3];
  float* out = (float*)d_out;

  char* ws = (char*)d_ws;
  unsigned short* W3t = (unsigned short*)ws;                          // 147456 B
  unsigned short* Qg  = (unsigned short*)(ws + 147456);               // 8388608 B
  unsigned short* Kg  = (unsigned short*)(ws + 147456 + 8388608);     // 8388608 B
  unsigned short* Vtg = (unsigned short*)(ws + 147456 + 16777216);    // 8388608 B

  hipFuncSetAttribute((const void*)attn_kernel,
                      hipFuncAttributeMaxDynamicSharedMemorySize, 75776);

  wconv_kernel<<<192, 384, 0, stream>>>(Wq, Wk, Wv, W3t);
  proj_kernel<<<512, 256, 0, stream>>>(x, W3t, Qg, Kg, Vtg);
  attn_kernel<<<256, 256, 75776, stream>>>(Qg, Kg, Vtg, out);
}

// Round 2
// 38.301 us; speedup vs baseline: 1.3678x; 1.3678x over previous
//
#include <hip/hip_runtime.h>
#include <hip/hip_bf16.h>

typedef __attribute__((ext_vector_type(8))) short short8;
typedef __attribute__((ext_vector_type(4))) float f32x4;

#define MFMA(a, b, c) __builtin_amdgcn_mfma_f32_16x16x32_bf16((a), (b), (c), 0, 0, 0)

__device__ __forceinline__ unsigned short f2bf(float f) {
  union { float f; unsigned int u; } v; v.f = f;
  unsigned int u = v.u;
  unsigned int r = u + 0x7FFFu + ((u >> 16) & 1u);  // RNE
  return (unsigned short)(r >> 16);
}

// ---------------------------------------------------------------------------
// Fully fused: per-batch block. Proj GEMM (x[256,384] @ W[384,192]) -> QKV in
// LDS -> causal attention -> out. 512 threads = 8 waves. LDS 143360 B:
//   Ql [256][72] bf16   @ 0      (18432 ush)
//   Kl [256][72] bf16   @ 18432  (18432 ush)
//   Vl [64][264] bf16   @ 36864  (16896 ush)   (V transposed: [h][token])
//   xl [256][40] bf16   @ 53760  (10240 ush)   (reused as P-xpose buf in attn)
//   wl [192][40] bf16   @ 64000  (7680 ush)    (W^T slice: [n][k])
// ---------------------------------------------------------------------------
__global__ __launch_bounds__(512) void fused_kernel(
    const float* __restrict__ x, const float* __restrict__ Wq,
    const float* __restrict__ Wk, const float* __restrict__ Wv,
    float* __restrict__ out) {
  extern __shared__ unsigned short sm[];
  unsigned short* Ql = sm;
  unsigned short* Kl = sm + 18432;
  unsigned short* Vl = sm + 36864;
  unsigned short* xl = sm + 53760;
  unsigned short* wl = sm + 64000;

  const int tid = threadIdx.x;  // 0..511
  const int w = tid >> 6, lane = tid & 63, g = lane >> 4, q = lane & 15;
  const int b = blockIdx.x;
  const float* xb = x + (long)b * 256 * 384;

  f32x4 acc[2][12];
  const f32x4 zf = {0.f, 0.f, 0.f, 0.f};
#pragma unroll
  for (int i = 0; i < 2; ++i)
#pragma unroll
    for (int j = 0; j < 12; ++j) acc[i][j] = zf;

  // ---- staging-register prefetch (T14 split: issue early, ds_write late) ----
  // x: 4 float4/thread: i = tid + it*512; r = i>>3 (row 0..255), c4 = (i&7)*4
  // W: 3 float4/thread: wr[it] from {Wq,Wk,Wv}[it]; k = tid&31, c = (tid>>5)&15
  //    (source elems n = 64*it + 4c + j, k-row k0+k)
  float4 xr[4];
  float4 wr[3];
  const int xk = tid & 31, xc = (tid >> 5) & 15;

  {  // prologue: issue loads for k0 = 0
    const int k0 = 0;
#pragma unroll
    for (int it = 0; it < 4; ++it) {
      int i = tid + it * 512;
      xr[it] = *(const float4*)&xb[(i >> 3) * 384 + k0 + (i & 7) * 4];
    }
    wr[0] = *(const float4*)&Wq[(k0 + xk) * 64 + xc * 4];
    wr[1] = *(const float4*)&Wk[(k0 + xk) * 64 + xc * 4];
    wr[2] = *(const float4*)&Wv[(k0 + xk) * 64 + xc * 4];
  }

  for (int s = 0; s < 12; ++s) {
    const int k0n = 32 * (s + 1);
    if (s) __syncthreads();  // all waves done reading previous tile's frags
    // ds_write current tile from regs
#pragma unroll
    for (int it = 0; it < 4; ++it) {
      int i = tid + it * 512;
      int r = i >> 3, c4 = (i & 7) * 4;
      ushort4 h;
      h.x = f2bf(xr[it].x); h.y = f2bf(xr[it].y);
      h.z = f2bf(xr[it].z); h.w = f2bf(xr[it].w);
      *(ushort4*)&xl[r * 40 + c4] = h;
    }
#pragma unroll
    for (int it = 0; it < 3; ++it) {
      int nb = 64 * it + 4 * xc;
      wl[(nb + 0) * 40 + xk] = f2bf(wr[it].x);
      wl[(nb + 1) * 40 + xk] = f2bf(wr[it].y);
      wl[(nb + 2) * 40 + xk] = f2bf(wr[it].z);
      wl[(nb + 3) * 40 + xk] = f2bf(wr[it].w);
    }
    // issue next tile's loads (latency hides under MFMA phase)
    if (s < 11) {
#pragma unroll
      for (int it = 0; it < 4; ++it) {
        int i = tid + it * 512;
        xr[it] = *(const float4*)&xb[(i >> 3) * 384 + k0n + (i & 7) * 4];
      }
      wr[0] = *(const float4*)&Wq[(k0n + xk) * 64 + xc * 4];
      wr[1] = *(const float4*)&Wk[(k0n + xk) * 64 + xc * 4];
      wr[2] = *(const float4*)&Wv[(k0n + xk) * 64 + xc * 4];
    }
    __syncthreads();
    // MFMA phase: wave w owns rows [32w, 32w+32)
    short8 a0 = *(const short8*)&xl[(32 * w + q) * 40 + g * 8];
    short8 a1 = *(const short8*)&xl[(32 * w + 16 + q) * 40 + g * 8];
#pragma unroll
    for (int ct = 0; ct < 12; ++ct) {
      short8 bfr = *(const short8*)&wl[(16 * ct + q) * 40 + g * 8];
      acc[0][ct] = MFMA(a0, bfr, acc[0][ct]);
      acc[1][ct] = MFMA(a1, bfr, acc[1][ct]);
    }
  }

  // ---- proj epilogue: QKV -> LDS (D layout: col=lane&15, row=4g+reg) ----
#pragma unroll
  for (int rt = 0; rt < 2; ++rt) {
    const int mb = 32 * w + 16 * rt + 4 * g;  // within-batch row
#pragma unroll
    for (int ct = 0; ct < 12; ++ct) {
      int c = 16 * ct + q;
      unsigned short h0 = f2bf(acc[rt][ct][0]);
      unsigned short h1 = f2bf(acc[rt][ct][1]);
      unsigned short h2 = f2bf(acc[rt][ct][2]);
      unsigned short h3 = f2bf(acc[rt][ct][3]);
      if (ct < 4) {
        Ql[(mb + 0) * 72 + c] = h0; Ql[(mb + 1) * 72 + c] = h1;
        Ql[(mb + 2) * 72 + c] = h2; Ql[(mb + 3) * 72 + c] = h3;
      } else if (ct < 8) {
        int cc = c - 64;
        Kl[(mb + 0) * 72 + cc] = h0; Kl[(mb + 1) * 72 + cc] = h1;
        Kl[(mb + 2) * 72 + cc] = h2; Kl[(mb + 3) * 72 + cc] = h3;
      } else {
        int hh = c - 128;
        ushort4 pk; pk.x = h0; pk.y = h1; pk.z = h2; pk.w = h3;
        *(ushort4*)&Vl[hh * 264 + mb] = pk;  // V^T[h][tok..tok+3]
      }
    }
  }
  __syncthreads();

  // ---- attention phase: wave w owns row-tiles {w, 15-w} (17 units each) ----
  unsigned short* Pb = xl + w * 640;  // per-wave [16][40] transpose buffer
  const int tt[2] = {w, 15 - w};
#pragma unroll
  for (int ti = 0; ti < 2; ++ti) {
    const int t = tt[ti];
    short8 aq0 = *(const short8*)&Ql[(16 * t + q) * 72 + g * 8];
    short8 aq1 = *(const short8*)&Ql[(16 * t + q) * 72 + 32 + g * 8];

    f32x4 s[16];  // compile-time indexed only -> VGPRs
#pragma unroll
    for (int j = 0; j < 16; ++j) {
      if (j <= t) {
        short8 bk0 = *(const short8*)&Kl[(16 * j + q) * 72 + g * 8];
        short8 bk1 = *(const short8*)&Kl[(16 * j + q) * 72 + 32 + g * 8];
        f32x4 sv = MFMA(aq0, bk0, zf);
        sv = MFMA(aq1, bk1, sv);
#pragma unroll
        for (int jr = 0; jr < 4; ++jr) {
          float v = sv[jr] * 0.125f;  // H^-0.5
          if (j == t && q > 4 * g + jr) v = -1e30f;  // causal (diagonal tile)
          sv[jr] = v;
        }
        s[j] = sv;
      }
    }

    // softmax: row r = 16t+4g+jr lives across the 16 lanes sharing g
    float mrow[4], lrow[4];
#pragma unroll
    for (int jr = 0; jr < 4; ++jr) {
      float m = -1e30f;
#pragma unroll
      for (int j = 0; j < 16; ++j)
        if (j <= t) m = fmaxf(m, s[j][jr]);
      m = fmaxf(m, __shfl_xor(m, 1));
      m = fmaxf(m, __shfl_xor(m, 2));
      m = fmaxf(m, __shfl_xor(m, 4));
      m = fmaxf(m, __shfl_xor(m, 8));
      mrow[jr] = m;
    }
#pragma unroll
    for (int jr = 0; jr < 4; ++jr) {
      float l = 0.0f;
#pragma unroll
      for (int j = 0; j < 16; ++j)
        if (j <= t) {
          float p = __expf(s[j][jr] - mrow[jr]);
          s[j][jr] = p;
          l += p;
        }
      l += __shfl_xor(l, 1);
      l += __shfl_xor(l, 2);
      l += __shfl_xor(l, 4);
      l += __shfl_xor(l, 8);
      lrow[jr] = l;
    }

    // PV: per 32-token slice, transpose P through per-wave LDS buffer
    f32x4 o[4];
#pragma unroll
    for (int ct = 0; ct < 4; ++ct) o[ct] = zf;
#pragma unroll
    for (int ks = 0; ks < 8; ++ks) {
      if (2 * ks <= t) {
#pragma unroll
        for (int half = 0; half < 2; ++half) {
          int tile = 2 * ks + half;
#pragma unroll
          for (int jr = 0; jr < 4; ++jr) {
            unsigned short pv = 0;
            if (tile <= t) pv = f2bf(s[tile][jr]);
            Pb[(4 * g + jr) * 40 + half * 16 + q] = pv;
          }
        }
        short8 ap = *(const short8*)&Pb[q * 40 + g * 8];
#pragma unroll
        for (int ct = 0; ct < 4; ++ct) {
          short8 bv = *(const short8*)&Vl[(16 * ct + q) * 264 + ks * 32 + g * 8];
          o[ct] = MFMA(ap, bv, o[ct]);
        }
      }
    }

    // epilogue: out fp32 [b][tok][h], fold in 1/rowsum
    const long rowbase = (long)b * 256 + 16 * t + 4 * g;
#pragma unroll
    for (int jr = 0; jr < 4; ++jr) {
      float inv = 1.0f / lrow[jr];
#pragma unroll
      for (int ct = 0; ct < 4; ++ct) {
        out[(rowbase + jr) * 64 + 16 * ct + q] = o[ct][jr] * inv;
      }
    }
  }
}

// ---------------------------------------------------------------------------
extern "C" void kernel_launch(void* const* d_in, const int* in_sizes, int n_in,
                              void* d_out, int out_size, void* d_ws, size_t ws_size,
                              hipStream_t stream) {
  const float* x  = (const float*)d_in[0];
  const float* Wq = (const float*)d_in[1];
  const float* Wk = (const float*)d_in[2];
  const float* Wv = (const float*)d_in[3];
  float* out = (float*)d_out;

  hipFuncSetAttribute((const void*)fused_kernel,
                      hipFuncAttributeMaxDynamicSharedMemorySize, 143360);
  fused_kernel<<<256, 512, 143360, stream>>>(x, Wq, Wk, Wv, out);
}